// Round 3
// baseline (729.143 us; speedup 1.0000x reference)
//
#include <hip/hip_runtime.h>
#include <hip/hip_fp16.h>

#define D 64
#define NKR 16
#define NB 1024
#define NL 8

typedef __attribute__((ext_vector_type(8))) _Float16 half8;
typedef __attribute__((ext_vector_type(16))) float f32x16;
typedef __attribute__((ext_vector_type(4))) int i32x4;

static __device__ __forceinline__ half8 neg8(half8 x) {
    i32x4 u = __builtin_bit_cast(i32x4, x);
    u = u ^ (int)0x80008000;
    return __builtin_bit_cast(half8, u);
}

static __device__ __forceinline__ unsigned pkrtz(float a, float b) {
    auto h = __builtin_amdgcn_cvt_pkrtz(a, b);   // __fp16 ext_vector_type(2)
    return __builtin_bit_cast(unsigned, h);
}

// v_permlane32_swap_b32: a.row1 <-> b.row0 (row = 32-lane half).
static __device__ __forceinline__ void plswap(unsigned &a, unsigned &b) {
    asm volatile("v_permlane32_swap_b32 %0, %1" : "+v"(a), "+v"(b));
}

union Pack4 { _Float16 h[4]; uint2 u; };
union H8 { unsigned u[4]; uint2 v[2]; half8 h; };

#define GLDS16(gp, lp) \
    __builtin_amdgcn_global_load_lds((const __attribute__((address_space(1))) void*)(gp), \
                                     (__attribute__((address_space(3))) void*)(lp), 16, 0, 0)

#define MFMA __builtin_amdgcn_mfma_f32_32x32x16_f16

// kraus fp32 -> fp16, layout [L][K][2][64][64] with XOR-swizzled 8B (4-half) granules:
// element (plane,row,col) -> plane*4096 + row*64 + (((col>>2)^(row&15))<<2) + (col&3)
__global__ void kconv_kernel(const float* __restrict__ re, const float* __restrict__ im,
                             _Float16* __restrict__ out) {
    int plane = blockIdx.y;
    int idx = blockIdx.x * blockDim.x + threadIdx.x;
    const float* src = plane ? im : re;
    float4 v = ((const float4*)src)[idx];
    int e = idx * 4;
    int lk = e >> 12;
    int rem = e & 4095;
    int row = rem >> 6, col = rem & 63;          // col multiple of 4 -> one granule
    int grp = (col >> 2) ^ (row & 15);
    Pack4 p;
    p.h[0] = (_Float16)v.x; p.h[1] = (_Float16)v.y;
    p.h[2] = (_Float16)v.z; p.h[3] = (_Float16)v.w;
    *(uint2*)(out + ((size_t)lk * 2 + plane) * 4096 + row * 64 + grp * 4) = p.u;
}

// state fp32 -> fp16 transposed: out[b][plane][l][j] = state[b][j][l]  (rho^T row-major)
__global__ void sconv_kernel(const float* __restrict__ re, const float* __restrict__ im,
                             _Float16* __restrict__ out) {
    __shared__ float tile[64][65];
    int b = blockIdx.x;
    int t = threadIdx.x;
    for (int plane = 0; plane < 2; ++plane) {
        const float* src = (plane ? im : re) + (size_t)b * 4096;
        __syncthreads();
        #pragma unroll
        for (int i = 0; i < 16; ++i) {
            int e = t + 256 * i;
            tile[e >> 6][e & 63] = src[e];
        }
        __syncthreads();
        _Float16* o = out + ((size_t)b * 2 + plane) * 4096;
        #pragma unroll
        for (int i = 0; i < 16; ++i) {
            int e = t + 256 * i;            // e = l*64 + j
            o[e] = (_Float16)tile[e & 63][e >> 6];
        }
    }
}

// Stage-1 f32x16 tile (lane=col i, reg 4g+j -> row l_rel=8g+4hl+j) -> two stage-2
// A-fragments (lane=row i, halves l_rel 16c+8hl+0..7) in registers: 8 cvt + 4 permlane.
static __device__ __forceinline__ void exchange(const f32x16 &dd, half8 &f0, half8 &f1) {
    unsigned A0 = pkrtz(dd[0],  dd[1]),  B0 = pkrtz(dd[2],  dd[3]);
    unsigned A1 = pkrtz(dd[4],  dd[5]),  B1 = pkrtz(dd[6],  dd[7]);
    unsigned A2 = pkrtz(dd[8],  dd[9]),  B2 = pkrtz(dd[10], dd[11]);
    unsigned A3 = pkrtz(dd[12], dd[13]), B3 = pkrtz(dd[14], dd[15]);
    plswap(A0, A1);
    plswap(B0, B1);
    plswap(A2, A3);
    plswap(B2, B3);
    H8 h0; h0.u[0] = A0; h0.u[1] = B0; h0.u[2] = A1; h0.u[3] = B1; f0 = h0.h;
    H8 h1; h1.u[0] = A2; h1.u[1] = B2; h1.u[2] = A3; h1.u[3] = B3; f1 = h1.h;
}

// Wave (IT, LH): stage 1 computes T^T[l in LH-half][i in IT-tile] (16 MFMAs), register
// exchange, stage 2 accumulates the LH-half of the l-contraction into BOTH m-tiles
// (16 MFMAs). acc is a partial sum over l; LH pairs are reduced once at the end.
template<int IT, int LH>
static __device__ __forceinline__ void kstep(
    const _Float16* __restrict__ KB,
    const half8 (&a1re)[4], const half8 (&a1im)[4],
    f32x16 (&accRe)[2], f32x16 (&accIm)[2],
    int l31, int hl)
{
    const int rx = l31 & 15;

    // ---- stage-1 B: K rows 32*IT + l31, all 4 ks cols, both planes ----
    half8 bre[4], bim[4];
    {
        const int base = (32 * IT + l31) * 64;
        #pragma unroll
        for (int ks = 0; ks < 4; ++ks) {
            const int g = 4 * ks + 2 * hl;
            const int p = ((g ^ rx) << 2);
            const int q = (((g + 1) ^ rx) << 2);
            H8 t;
            t.v[0] = *(const uint2*)&KB[base + p];
            t.v[1] = *(const uint2*)&KB[base + q];
            bre[ks] = t.h;
            t.v[0] = *(const uint2*)&KB[4096 + base + p];
            t.v[1] = *(const uint2*)&KB[4096 + base + q];
            bim[ks] = t.h;
        }
    }

    // ---- stage 1: one 32x32 T^T tile (re+im) ----
    f32x16 ddre, ddim;
    #pragma unroll
    for (int i = 0; i < 16; ++i) { ddre[i] = 0.f; ddim[i] = 0.f; }
    #pragma unroll
    for (int ks = 0; ks < 4; ++ks) {
        half8 bn = neg8(bim[ks]);
        ddre = MFMA(a1re[ks], bre[ks], ddre, 0, 0, 0);
        ddre = MFMA(a1im[ks], bn,      ddre, 0, 0, 0);
        ddim = MFMA(a1re[ks], bim[ks], ddim, 0, 0, 0);
        ddim = MFMA(a1im[ks], bre[ks], ddim, 0, 0, 0);
    }

    half8 afre[2], afim[2], afn[2];
    exchange(ddre, afre[0], afre[1]);
    exchange(ddim, afim[0], afim[1]);
    afn[0] = neg8(afre[0]);
    afn[1] = neg8(afre[1]);

    // ---- stage 2, mt = IT: B reused from stage 1 (ks slots 2LH, 2LH+1) ----
    #pragma unroll
    for (int c = 0; c < 2; ++c) {
        accRe[IT] = MFMA(afre[c], bre[2 * LH + c], accRe[IT], 0, 0, 0);
        accRe[IT] = MFMA(afim[c], bim[2 * LH + c], accRe[IT], 0, 0, 0);
        accIm[IT] = MFMA(afim[c], bre[2 * LH + c], accIm[IT], 0, 0, 0);
        accIm[IT] = MFMA(afn[c],  bim[2 * LH + c], accIm[IT], 0, 0, 0);
    }

    // ---- stage 2, mt = 1-IT: fresh B rows 32*(1-IT)+l31, cols ksl = 2LH+c ----
    {
        const int base = (32 * (1 - IT) + l31) * 64;
        #pragma unroll
        for (int c = 0; c < 2; ++c) {
            const int g = 8 * LH + 4 * c + 2 * hl;
            const int p = ((g ^ rx) << 2);
            const int q = (((g + 1) ^ rx) << 2);
            H8 t;
            t.v[0] = *(const uint2*)&KB[base + p];
            t.v[1] = *(const uint2*)&KB[base + q];
            half8 br = t.h;
            t.v[0] = *(const uint2*)&KB[4096 + base + p];
            t.v[1] = *(const uint2*)&KB[4096 + base + q];
            half8 bi = t.h;
            accRe[1 - IT] = MFMA(afre[c], br, accRe[1 - IT], 0, 0, 0);
            accRe[1 - IT] = MFMA(afim[c], bi, accRe[1 - IT], 0, 0, 0);
            accIm[1 - IT] = MFMA(afim[c], br, accIm[1 - IT], 0, 0, 0);
            accIm[1 - IT] = MFMA(afn[c],  bi, accIm[1 - IT], 0, 0, 0);
        }
    }
}

// One block per rho (1024 blocks -> 4/CU schedulable; launch_bounds(256,3) caps regs
// at 170 for 3 resident blocks = 12 waves/CU, up from 8). Wave (IT=wv&1, LH=wv>>1).
// K double-buffered in LDS, 1 barrier/kraus; LH-pair acc reduction once per layer.
__global__ __launch_bounds__(256, 3) void layer_kernel(
    const _Float16* __restrict__ rho_in,
    _Float16* __restrict__ rho_out,
    float* __restrict__ final_out,
    const _Float16* __restrict__ kraus,   // this layer, swizzled: [K][2][64][64]
    int last)
{
    __shared__ __align__(16) _Float16 Klds[2][2 * D * D];     // 2 x 16 KB double buffer

    const int b    = blockIdx.x;
    const int t    = threadIdx.x;
    const int wv   = t >> 6;
    const int lane = t & 63;
    const int l31  = lane & 31;
    const int hl   = lane >> 5;
    const int IT   = wv & 1;
    const int LH   = wv >> 1;

    // ---- hoisted A1: rho^T rows 32*LH + l31 (this wave's l-half only) ----
    half8 a1re[4], a1im[4];
    {
        const _Float16* rb = rho_in + (size_t)b * 2 * D * D;
        const int row = 32 * LH + l31;
        #pragma unroll
        for (int ks = 0; ks < 4; ++ks) {
            const int col = 16 * ks + 8 * hl;
            a1re[ks] = *(const half8*)(rb + row * D + col);
            a1im[ks] = *(const half8*)(rb + D * D + row * D + col);
        }
    }

    // ---- preload K_0 into Klds[0] (async, drained by barrier) ----
    {
        const char* kb = (const char*)kraus;
        const int off = wv * 4096;
        #pragma unroll
        for (int rr = 0; rr < 4; ++rr)
            GLDS16(kb + off + rr * 1024 + lane * 16, (char*)&Klds[0][0] + off + rr * 1024);
    }

    f32x16 accRe[2], accIm[2];
    #pragma unroll
    for (int mt = 0; mt < 2; ++mt)
        #pragma unroll
        for (int i = 0; i < 16; ++i) { accRe[mt][i] = 0.f; accIm[mt][i] = 0.f; }

    __syncthreads();

    #pragma unroll 1
    for (int k = 0; k < NKR; ++k) {
        if (k + 1 < NKR) {
            const char* kb = (const char*)(kraus + (size_t)(k + 1) * 2 * D * D);
            const int off = wv * 4096;
            #pragma unroll
            for (int rr = 0; rr < 4; ++rr)
                GLDS16(kb + off + rr * 1024 + lane * 16,
                       (char*)&Klds[(k + 1) & 1][0] + off + rr * 1024);
        }
        const _Float16* KB = &Klds[0][0] + (k & 1) * (2 * D * D);
        switch (wv) {
            case 0: kstep<0, 0>(KB, a1re, a1im, accRe, accIm, l31, hl); break;
            case 1: kstep<1, 0>(KB, a1re, a1im, accRe, accIm, l31, hl); break;
            case 2: kstep<0, 1>(KB, a1re, a1im, accRe, accIm, l31, hl); break;
            default: kstep<1, 1>(KB, a1re, a1im, accRe, accIm, l31, hl); break;
        }
        __syncthreads();
    }

    // ---- cross-wave reduction of the l-half partials (LH=1 -> LH=0), then write ----
    float* red = (float*)&Klds[0][0];     // 32 KB, [IT][idx][lane], conflict-free
    if (LH == 1) {
        const int base = IT * 4096;
        #pragma unroll
        for (int mt = 0; mt < 2; ++mt)
            #pragma unroll
            for (int i = 0; i < 16; ++i) {
                red[base + (mt * 32 + i) * 64 + lane]      = accRe[mt][i];
                red[base + (mt * 32 + 16 + i) * 64 + lane] = accIm[mt][i];
            }
    }
    __syncthreads();
    if (LH == 0) {
        const int base = IT * 4096;
        #pragma unroll
        for (int mt = 0; mt < 2; ++mt)
            #pragma unroll
            for (int i = 0; i < 16; ++i) {
                accRe[mt][i] += red[base + (mt * 32 + i) * 64 + lane];
                accIm[mt][i] += red[base + (mt * 32 + 16 + i) * 64 + lane];
            }

        // epilogue: acc lane=col m_rel, reg 4g+j -> row i = 32*IT + 8g + 4hl + j
        if (!last) {
            _Float16* ob = rho_out + (size_t)b * 2 * D * D;
            #pragma unroll
            for (int mt = 0; mt < 2; ++mt) {
                const int m = 32 * mt + l31;
                #pragma unroll
                for (int g = 0; g < 4; ++g) {
                    Pack4 pr, pi;
                    #pragma unroll
                    for (int j = 0; j < 4; ++j) {
                        pr.h[j] = (_Float16)accRe[mt][4 * g + j];
                        pi.h[j] = (_Float16)accIm[mt][4 * g + j];
                    }
                    const int i0 = 32 * IT + 8 * g + 4 * hl;
                    *(uint2*)(ob + m * D + i0)         = pr.u;   // rho_new^T[m][i]
                    *(uint2*)(ob + D * D + m * D + i0) = pi.u;
                }
            }
        } else {
            float* o0 = final_out + (size_t)b * 4096;            // [0][b][i][m]
            float* o1 = final_out + (size_t)(NB + b) * 4096;     // [1][b][i][m]
            #pragma unroll
            for (int mt = 0; mt < 2; ++mt) {
                const int m = 32 * mt + l31;
                #pragma unroll
                for (int g = 0; g < 4; ++g) {
                    #pragma unroll
                    for (int j = 0; j < 4; ++j) {
                        const int i = 32 * IT + 8 * g + 4 * hl + j;
                        o0[i * D + m] = accRe[mt][4 * g + j];
                        o1[i * D + m] = accIm[mt][4 * g + j];
                    }
                }
            }
        }
    }
}

extern "C" void kernel_launch(void* const* d_in, const int* in_sizes, int n_in,
                              void* d_out, int out_size, void* d_ws, size_t ws_size,
                              hipStream_t stream) {
    const float* state_re = (const float*)d_in[0];
    const float* state_im = (const float*)d_in[1];
    const float* kraus_re = (const float*)d_in[2];
    const float* kraus_im = (const float*)d_in[3];

    _Float16* kraus_h = (_Float16*)d_ws;                         // 2 MB in ws (swizzled)
    // ping-pong rho buffers live inside d_out (2 x 16 MB = out_size exactly).
    _Float16* bufA = (_Float16*)d_out;
    _Float16* bufB = (_Float16*)((char*)d_out + (size_t)NB * 2 * D * D * sizeof(_Float16));
    float* fout = (float*)d_out;

    kconv_kernel<<<dim3(512, 2), 256, 0, stream>>>(kraus_re, kraus_im, kraus_h);
    sconv_kernel<<<NB, 256, 0, stream>>>(state_re, state_im, bufA);

    for (int l = 0; l < NL; ++l) {
        const _Float16* in = (l & 1) ? bufB : bufA;
        _Float16* out      = (l & 1) ? bufA : bufB;
        layer_kernel<<<NB, 256, 0, stream>>>(in, out, fout,
                                             kraus_h + (size_t)l * NKR * 2 * D * D,
                                             (l == NL - 1) ? 1 : 0);
    }
}

// Round 4
// 572.799 us; speedup vs baseline: 1.2729x; 1.2729x over previous
//
#include <hip/hip_runtime.h>
#include <hip/hip_fp16.h>

#define D 64
#define NKR 16
#define NB 1024
#define NL 8

typedef __attribute__((ext_vector_type(8))) _Float16 half8;
typedef __attribute__((ext_vector_type(16))) float f32x16;
typedef __attribute__((ext_vector_type(4))) int i32x4;

static __device__ __forceinline__ half8 neg8(half8 x) {
    i32x4 u = __builtin_bit_cast(i32x4, x);
    u = u ^ (int)0x80008000;
    return __builtin_bit_cast(half8, u);
}

static __device__ __forceinline__ unsigned pkrtz(float a, float b) {
    auto h = __builtin_amdgcn_cvt_pkrtz(a, b);   // __fp16 ext_vector_type(2)
    return __builtin_bit_cast(unsigned, h);
}

// v_permlane32_swap_b32: a.row1 <-> b.row0 (row = 32-lane half).
static __device__ __forceinline__ void plswap(unsigned &a, unsigned &b) {
    asm volatile("v_permlane32_swap_b32 %0, %1" : "+v"(a), "+v"(b));
}

union Pack4 { _Float16 h[4]; uint2 u; };
union H8 { unsigned u[4]; uint2 v[2]; half8 h; };

#define GLDS16(gp, lp) \
    __builtin_amdgcn_global_load_lds((const __attribute__((address_space(1))) void*)(gp), \
                                     (__attribute__((address_space(3))) void*)(lp), 16, 0, 0)

#define MFMA __builtin_amdgcn_mfma_f32_32x32x16_f16

// kraus fp32 -> fp16, layout [L][K][2][64][64] with XOR-swizzled 8B (4-half) granules:
// element (plane,row,col) -> plane*4096 + row*64 + (((col>>2)^(row&15))<<2) + (col&3)
__global__ void kconv_kernel(const float* __restrict__ re, const float* __restrict__ im,
                             _Float16* __restrict__ out) {
    int plane = blockIdx.y;
    int idx = blockIdx.x * blockDim.x + threadIdx.x;
    const float* src = plane ? im : re;
    float4 v = ((const float4*)src)[idx];
    int e = idx * 4;
    int lk = e >> 12;
    int rem = e & 4095;
    int row = rem >> 6, col = rem & 63;          // col multiple of 4 -> one granule
    int grp = (col >> 2) ^ (row & 15);
    Pack4 p;
    p.h[0] = (_Float16)v.x; p.h[1] = (_Float16)v.y;
    p.h[2] = (_Float16)v.z; p.h[3] = (_Float16)v.w;
    *(uint2*)(out + ((size_t)lk * 2 + plane) * 4096 + row * 64 + grp * 4) = p.u;
}

// state fp32 -> fp16 transposed: out[b][plane][l][j] = state[b][j][l]  (rho^T row-major)
__global__ void sconv_kernel(const float* __restrict__ re, const float* __restrict__ im,
                             _Float16* __restrict__ out) {
    __shared__ float tile[64][65];
    int b = blockIdx.x;
    int t = threadIdx.x;
    for (int plane = 0; plane < 2; ++plane) {
        const float* src = (plane ? im : re) + (size_t)b * 4096;
        __syncthreads();
        #pragma unroll
        for (int i = 0; i < 16; ++i) {
            int e = t + 256 * i;
            tile[e >> 6][e & 63] = src[e];
        }
        __syncthreads();
        _Float16* o = out + ((size_t)b * 2 + plane) * 4096;
        #pragma unroll
        for (int i = 0; i < 16; ++i) {
            int e = t + 256 * i;            // e = l*64 + j
            o[e] = (_Float16)tile[e & 63][e >> 6];
        }
    }
}

// Stage-1 f32x16 tile (lane=col i, reg 4g+j -> row l_rel=8g+4hl+j) -> two stage-2
// A-fragments (lane=row i, halves l_rel 16c+8hl+0..7) in registers: 8 cvt + 4 permlane.
static __device__ __forceinline__ void exchange(const f32x16 &dd, half8 &f0, half8 &f1) {
    unsigned A0 = pkrtz(dd[0],  dd[1]),  B0 = pkrtz(dd[2],  dd[3]);
    unsigned A1 = pkrtz(dd[4],  dd[5]),  B1 = pkrtz(dd[6],  dd[7]);
    unsigned A2 = pkrtz(dd[8],  dd[9]),  B2 = pkrtz(dd[10], dd[11]);
    unsigned A3 = pkrtz(dd[12], dd[13]), B3 = pkrtz(dd[14], dd[15]);
    plswap(A0, A1);
    plswap(B0, B1);
    plswap(A2, A3);
    plswap(B2, B3);
    H8 h0; h0.u[0] = A0; h0.u[1] = B0; h0.u[2] = A1; h0.u[3] = B1; f0 = h0.h;
    H8 h1; h1.u[0] = A2; h1.u[1] = B2; h1.u[2] = A3; h1.u[3] = B3; f1 = h1.h;
}

// One kraus step for a wave owning output i-tile IT of one rho (round-2 structure:
// 64 MFMAs/wave/k). Stage 1: T^T tiles for i in IT-tile, both l-halves; register
// exchange; stage 2: both m-tiles, B for mt=IT reused from stage 1, mt=1-IT fresh.
template<int IT>
static __device__ __forceinline__ void kstep(
    const _Float16* __restrict__ KB,
    const half8 (&a1re)[2][4], const half8 (&a1im)[2][4],
    f32x16 (&accRe)[2], f32x16 (&accIm)[2],
    int l31, int hl)
{
    const int rx = l31 & 15;

    // ---- B(mt=IT): rows 32*IT + l31; 2x ds_read_b64 per half8 (swizzled granules) ----
    half8 bre0[4], bim0[4], bimn[4];
    {
        const int base = (32 * IT + l31) * 64;
        #pragma unroll
        for (int ks = 0; ks < 4; ++ks) {
            const int g = 4 * ks + 2 * hl;                 // even
            const int p = ((g ^ rx) << 2);
            const int q = (((g + 1) ^ rx) << 2);
            H8 t;
            t.v[0] = *(const uint2*)&KB[base + p];
            t.v[1] = *(const uint2*)&KB[base + q];
            bre0[ks] = t.h;
            t.v[0] = *(const uint2*)&KB[4096 + base + p];
            t.v[1] = *(const uint2*)&KB[4096 + base + q];
            bim0[ks] = t.h;
            bimn[ks] = neg8(bim0[ks]);
        }
    }

    // ---- stage 1: dd[lh] = T^T tile; then register exchange -> A-frags ----
    half8 af_re[4], af_im[4];
    #pragma unroll
    for (int lh = 0; lh < 2; ++lh) {
        f32x16 ddre, ddim;
        #pragma unroll
        for (int i = 0; i < 16; ++i) { ddre[i] = 0.f; ddim[i] = 0.f; }
        #pragma unroll
        for (int ks = 0; ks < 4; ++ks) {
            ddre = MFMA(a1re[lh][ks], bre0[ks], ddre, 0, 0, 0);
            ddre = MFMA(a1im[lh][ks], bimn[ks], ddre, 0, 0, 0);
            ddim = MFMA(a1re[lh][ks], bim0[ks], ddim, 0, 0, 0);
            ddim = MFMA(a1im[lh][ks], bre0[ks], ddim, 0, 0, 0);
        }
        exchange(ddre, af_re[2 * lh], af_re[2 * lh + 1]);
        exchange(ddim, af_im[2 * lh], af_im[2 * lh + 1]);
    }

    // ---- stage 2, mt = IT (B reused from stage 1) ----
    #pragma unroll
    for (int ks = 0; ks < 4; ++ks) {
        half8 an = neg8(af_re[ks]);
        accRe[IT] = MFMA(af_re[ks], bre0[ks], accRe[IT], 0, 0, 0);
        accRe[IT] = MFMA(af_im[ks], bim0[ks], accRe[IT], 0, 0, 0);
        accIm[IT] = MFMA(af_im[ks], bre0[ks], accIm[IT], 0, 0, 0);
        accIm[IT] = MFMA(an,        bim0[ks], accIm[IT], 0, 0, 0);
    }

    // ---- stage 2, mt = 1-IT (fresh B, per-ks to bound liveness) ----
    {
        const int base = (32 * (1 - IT) + l31) * 64;
        #pragma unroll
        for (int ks = 0; ks < 4; ++ks) {
            const int g = 4 * ks + 2 * hl;
            const int p = ((g ^ rx) << 2);
            const int q = (((g + 1) ^ rx) << 2);
            H8 t;
            t.v[0] = *(const uint2*)&KB[base + p];
            t.v[1] = *(const uint2*)&KB[base + q];
            half8 br = t.h;
            t.v[0] = *(const uint2*)&KB[4096 + base + p];
            t.v[1] = *(const uint2*)&KB[4096 + base + q];
            half8 bi = t.h;
            half8 an = neg8(af_re[ks]);
            accRe[1 - IT] = MFMA(af_re[ks], br, accRe[1 - IT], 0, 0, 0);
            accRe[1 - IT] = MFMA(af_im[ks], bi, accRe[1 - IT], 0, 0, 0);
            accIm[1 - IT] = MFMA(af_im[ks], br, accIm[1 - IT], 0, 0, 0);
            accIm[1 - IT] = MFMA(an,        bi, accIm[1 - IT], 0, 0, 0);
        }
    }
}

// One block per rho, 128 threads = 2 waves (IT = wave id). Same per-wave work as the
// round-2 kernel (64 MFMAs/k) but 4 independent blocks/CU at free-running k-phases and
// a 2-wave barrier instead of 4-wave -> off-phase blocks fill MFMA-pipe gaps.
__global__ __launch_bounds__(128, 2) void layer_kernel(
    const _Float16* __restrict__ rho_in,
    _Float16* __restrict__ rho_out,
    float* __restrict__ final_out,
    const _Float16* __restrict__ kraus,   // this layer, swizzled: [K][2][64][64]
    int last)
{
    __shared__ __align__(16) _Float16 Klds[2][2 * D * D];     // 2 x 16 KB double buffer

    const int b    = blockIdx.x;
    const int t    = threadIdx.x;
    const int wv   = t >> 6;              // 0..1 = output i-tile
    const int lane = t & 63;
    const int l31  = lane & 31;
    const int hl   = lane >> 5;

    // ---- hoisted A1: full rho^T (rows 32*lh + l31) for this block's rho ----
    half8 a1re[2][4], a1im[2][4];
    {
        const _Float16* rb = rho_in + (size_t)b * 2 * D * D;
        #pragma unroll
        for (int lh = 0; lh < 2; ++lh) {
            const int row = 32 * lh + l31;
            #pragma unroll
            for (int ks = 0; ks < 4; ++ks) {
                const int col = 16 * ks + 8 * hl;
                a1re[lh][ks] = *(const half8*)(rb + row * D + col);
                a1im[lh][ks] = *(const half8*)(rb + D * D + row * D + col);
            }
        }
    }

    // ---- preload K_0 into Klds[0] (async, drained by barrier); 8 KB per wave ----
    {
        const char* kb = (const char*)kraus;
        const int off = wv * 8192;
        #pragma unroll
        for (int rr = 0; rr < 8; ++rr)
            GLDS16(kb + off + rr * 1024 + lane * 16, (char*)&Klds[0][0] + off + rr * 1024);
    }

    f32x16 accRe[2], accIm[2];
    #pragma unroll
    for (int mt = 0; mt < 2; ++mt)
        #pragma unroll
        for (int i = 0; i < 16; ++i) { accRe[mt][i] = 0.f; accIm[mt][i] = 0.f; }

    __syncthreads();

    #pragma unroll 1
    for (int k = 0; k < NKR; ++k) {
        // async prefetch K_{k+1} into the other buffer; drained by end-of-iter barrier.
        if (k + 1 < NKR) {
            const char* kb = (const char*)(kraus + (size_t)(k + 1) * 2 * D * D);
            const int off = wv * 8192;
            #pragma unroll
            for (int rr = 0; rr < 8; ++rr)
                GLDS16(kb + off + rr * 1024 + lane * 16,
                       (char*)&Klds[(k + 1) & 1][0] + off + rr * 1024);
        }
        const _Float16* KB = &Klds[0][0] + (k & 1) * (2 * D * D);
        if (wv == 0) kstep<0>(KB, a1re, a1im, accRe, accIm, l31, hl);
        else         kstep<1>(KB, a1re, a1im, accRe, accIm, l31, hl);
        __syncthreads();
    }

    // ---- epilogue: acc lane=col m_rel, reg 4g+j -> row i = 32*IT + 8g + 4hl + j ----
    const int IT = wv;
    if (!last) {
        _Float16* ob = rho_out + (size_t)b * 2 * D * D;
        #pragma unroll
        for (int mt = 0; mt < 2; ++mt) {
            const int m = 32 * mt + l31;
            #pragma unroll
            for (int g = 0; g < 4; ++g) {
                Pack4 pr, pi;
                #pragma unroll
                for (int j = 0; j < 4; ++j) {
                    pr.h[j] = (_Float16)accRe[mt][4 * g + j];
                    pi.h[j] = (_Float16)accIm[mt][4 * g + j];
                }
                const int i0 = 32 * IT + 8 * g + 4 * hl;
                *(uint2*)(ob + m * D + i0)         = pr.u;   // rho_new^T[m][i]
                *(uint2*)(ob + D * D + m * D + i0) = pi.u;
            }
        }
    } else {
        float* o0 = final_out + (size_t)b * 4096;            // [0][b][i][m]
        float* o1 = final_out + (size_t)(NB + b) * 4096;     // [1][b][i][m]
        #pragma unroll
        for (int mt = 0; mt < 2; ++mt) {
            const int m = 32 * mt + l31;
            #pragma unroll
            for (int g = 0; g < 4; ++g) {
                #pragma unroll
                for (int j = 0; j < 4; ++j) {
                    const int i = 32 * IT + 8 * g + 4 * hl + j;
                    o0[i * D + m] = accRe[mt][4 * g + j];
                    o1[i * D + m] = accIm[mt][4 * g + j];
                }
            }
        }
    }
}

extern "C" void kernel_launch(void* const* d_in, const int* in_sizes, int n_in,
                              void* d_out, int out_size, void* d_ws, size_t ws_size,
                              hipStream_t stream) {
    const float* state_re = (const float*)d_in[0];
    const float* state_im = (const float*)d_in[1];
    const float* kraus_re = (const float*)d_in[2];
    const float* kraus_im = (const float*)d_in[3];

    _Float16* kraus_h = (_Float16*)d_ws;                         // 2 MB in ws (swizzled)
    // ping-pong rho buffers live inside d_out (2 x 16 MB = out_size exactly).
    _Float16* bufA = (_Float16*)d_out;
    _Float16* bufB = (_Float16*)((char*)d_out + (size_t)NB * 2 * D * D * sizeof(_Float16));
    float* fout = (float*)d_out;

    kconv_kernel<<<dim3(512, 2), 256, 0, stream>>>(kraus_re, kraus_im, kraus_h);
    sconv_kernel<<<NB, 256, 0, stream>>>(state_re, state_im, bufA);

    for (int l = 0; l < NL; ++l) {
        const _Float16* in = (l & 1) ? bufB : bufA;
        _Float16* out      = (l & 1) ? bufA : bufB;
        layer_kernel<<<NB, 128, 0, stream>>>(in, out, fout,
                                             kraus_h + (size_t)l * NKR * 2 * D * D,
                                             (l == NL - 1) ? 1 : 0);
    }
}

// Round 6
// 544.669 us; speedup vs baseline: 1.3387x; 1.0516x over previous
//
#include <hip/hip_runtime.h>
#include <hip/hip_fp16.h>

#define D 64
#define NKR 16
#define NB 1024
#define NL 8

typedef __attribute__((ext_vector_type(8))) _Float16 half8;
typedef __attribute__((ext_vector_type(16))) float f32x16;
typedef __attribute__((ext_vector_type(4))) int i32x4;

static __device__ __forceinline__ half8 neg8(half8 x) {
    i32x4 u = __builtin_bit_cast(i32x4, x);
    u = u ^ (int)0x80008000;
    return __builtin_bit_cast(half8, u);
}

static __device__ __forceinline__ unsigned pkrtz(float a, float b) {
    auto h = __builtin_amdgcn_cvt_pkrtz(a, b);   // __fp16 ext_vector_type(2)
    return __builtin_bit_cast(unsigned, h);
}

// v_permlane32_swap_b32: a.row1 <-> b.row0 (row = 32-lane half).
static __device__ __forceinline__ void plswap(unsigned &a, unsigned &b) {
    asm volatile("v_permlane32_swap_b32 %0, %1" : "+v"(a), "+v"(b));
}

union Pack4 { _Float16 h[4]; uint2 u; };
union H8 { unsigned u[4]; uint2 v[2]; half8 h; };

#define MFMA __builtin_amdgcn_mfma_f32_32x32x16_f16

// ---------------------------------------------------------------------------
// Fragment-order layout for 64x64 f16 matrices (both kraus and rho^T):
//   element (row, col) -> ihalf*2048 + (2*(col>>4) + ((col>>3)&1))*256 + (row&31)*8 + (col&7)
//   with ihalf = row>>5.  A wave's MFMA fragment (ks) for half ih is then ONE fully
//   coalesced 16B/lane load at: base + ih*2048 + ks*512 + lane*8   (halves).
// ---------------------------------------------------------------------------

// kraus fp32 -> fp16 fragment order: [L*K][plane][ihalf][slot][l31][8]
__global__ void kconv_kernel(const float* __restrict__ re, const float* __restrict__ im,
                             _Float16* __restrict__ out) {
    int plane = blockIdx.y;
    int idx = blockIdx.x * blockDim.x + threadIdx.x;
    const float* src = plane ? im : re;
    float4 v = ((const float4*)src)[idx];
    int e = idx * 4;
    int lk = e >> 12;
    int rem = e & 4095;
    int row = rem >> 6, col = rem & 63;          // col multiple of 4
    int ihalf = row >> 5, r31 = row & 31;
    int ks = col >> 4, hl2 = (col >> 3) & 1, c = col & 7;   // c in {0,4}
    Pack4 p;
    p.h[0] = (_Float16)v.x; p.h[1] = (_Float16)v.y;
    p.h[2] = (_Float16)v.z; p.h[3] = (_Float16)v.w;
    size_t off = (size_t)(lk * 2 + plane) * 4096 + ihalf * 2048
               + (2 * ks + hl2) * 256 + r31 * 8 + c;
    *(uint2*)(out + off) = p.u;
}

// state fp32 -> fp16, rho^T in fragment order: out[b][plane][fragment-layout of rho^T]
__global__ void sconv_kernel(const float* __restrict__ re, const float* __restrict__ im,
                             _Float16* __restrict__ out) {
    __shared__ float tile[64][65];
    int b = blockIdx.x;
    int t = threadIdx.x;
    for (int plane = 0; plane < 2; ++plane) {
        const float* src = (plane ? im : re) + (size_t)b * 4096;
        __syncthreads();
        #pragma unroll
        for (int i = 0; i < 16; ++i) {
            int e = t + 256 * i;
            tile[e >> 6][e & 63] = src[e];          // tile[i][j] = state[i][j]
        }
        __syncthreads();
        _Float16* o = out + ((size_t)b * 2 + plane) * 4096;
        #pragma unroll
        for (int i = 0; i < 16; ++i) {
            int oi = t + 256 * i;
            int lh = oi >> 11, slot = (oi >> 8) & 7, r = (oi >> 3) & 31, c = oi & 7;
            int col = 16 * (slot >> 1) + 8 * (slot & 1) + c;
            int row = 32 * lh + r;
            o[oi] = (_Float16)tile[col][row];       // rho^T[row][col] = state[col][row]
        }
    }
}

// Stage-1 f32x16 tile (lane=col i, reg 4g+j -> row l_rel=8g+4hl+j) -> two stage-2
// A-fragments (lane=row i, halves l_rel 16c+8hl+0..7) in registers: 8 cvt + 4 permlane.
static __device__ __forceinline__ void exchange(const f32x16 &dd, half8 &f0, half8 &f1) {
    unsigned A0 = pkrtz(dd[0],  dd[1]),  B0 = pkrtz(dd[2],  dd[3]);
    unsigned A1 = pkrtz(dd[4],  dd[5]),  B1 = pkrtz(dd[6],  dd[7]);
    unsigned A2 = pkrtz(dd[8],  dd[9]),  B2 = pkrtz(dd[10], dd[11]);
    unsigned A3 = pkrtz(dd[12], dd[13]), B3 = pkrtz(dd[14], dd[15]);
    plswap(A0, A1);
    plswap(B0, B1);
    plswap(A2, A3);
    plswap(B2, B3);
    H8 h0; h0.u[0] = A0; h0.u[1] = B0; h0.u[2] = A1; h0.u[3] = B1; f0 = h0.h;
    H8 h1; h1.u[0] = A2; h1.u[1] = B2; h1.u[2] = A3; h1.u[3] = B3; f1 = h1.h;
}

// One kraus step, all operands from global (L1/L2-resident K, fragment-order layout).
// Interleaved: stage1(lh) -> exchange -> stage2 slices 2lh,2lh+1 (both m-tiles), so
// dd and af live ranges stay short. 64 MFMAs, 16 coalesced dwordx4 loads, no LDS.
template<int IT>
static __device__ __forceinline__ void kstep(
    const _Float16* __restrict__ kb,     // this k: [plane][ihalf][slot][l31][8]
    const half8 (&a1re)[2][4], const half8 (&a1im)[2][4],
    f32x16 (&accRe)[2], f32x16 (&accIm)[2],
    int lane)
{
    const _Float16* bo = kb + IT * 2048;          // own half (stage1 B + stage2 mt=IT)
    const _Float16* bx = kb + (1 - IT) * 2048;    // other half (stage2 mt=1-IT)

    half8 bre[4], bim[4];
    #pragma unroll
    for (int ks = 0; ks < 4; ++ks) {
        bre[ks] = *(const half8*)(bo + ks * 512 + lane * 8);
        bim[ks] = *(const half8*)(bo + 4096 + ks * 512 + lane * 8);
    }

    #pragma unroll
    for (int lh = 0; lh < 2; ++lh) {
        f32x16 ddre, ddim;
        #pragma unroll
        for (int i = 0; i < 16; ++i) { ddre[i] = 0.f; ddim[i] = 0.f; }
        __builtin_amdgcn_s_setprio(1);
        #pragma unroll
        for (int ks = 0; ks < 4; ++ks) {
            half8 bn = neg8(bim[ks]);
            ddre = MFMA(a1re[lh][ks], bre[ks], ddre, 0, 0, 0);
            ddre = MFMA(a1im[lh][ks], bn,      ddre, 0, 0, 0);
            ddim = MFMA(a1re[lh][ks], bim[ks], ddim, 0, 0, 0);
            ddim = MFMA(a1im[lh][ks], bre[ks], ddim, 0, 0, 0);
        }
        __builtin_amdgcn_s_setprio(0);

        // other-half B for this lh's two l-slices: issue before exchange (latency hides)
        half8 br2[2], bi2[2];
        #pragma unroll
        for (int c = 0; c < 2; ++c) {
            const int ks = 2 * lh + c;
            br2[c] = *(const half8*)(bx + ks * 512 + lane * 8);
            bi2[c] = *(const half8*)(bx + 4096 + ks * 512 + lane * 8);
        }

        half8 fre0, fre1, fim0, fim1;
        exchange(ddre, fre0, fre1);
        exchange(ddim, fim0, fim1);

        #pragma unroll
        for (int c = 0; c < 2; ++c) {
            const int ks = 2 * lh + c;
            half8 afre = c ? fre1 : fre0;
            half8 afim = c ? fim1 : fim0;
            half8 an  = neg8(afre);
            __builtin_amdgcn_s_setprio(1);
            accRe[IT]     = MFMA(afre, bre[ks], accRe[IT], 0, 0, 0);
            accRe[IT]     = MFMA(afim, bim[ks], accRe[IT], 0, 0, 0);
            accIm[IT]     = MFMA(afim, bre[ks], accIm[IT], 0, 0, 0);
            accIm[IT]     = MFMA(an,   bim[ks], accIm[IT], 0, 0, 0);
            accRe[1 - IT] = MFMA(afre, br2[c],  accRe[1 - IT], 0, 0, 0);
            accRe[1 - IT] = MFMA(afim, bi2[c],  accRe[1 - IT], 0, 0, 0);
            accIm[1 - IT] = MFMA(afim, br2[c],  accIm[1 - IT], 0, 0, 0);
            accIm[1 - IT] = MFMA(an,   bi2[c],  accIm[1 - IT], 0, 0, 0);  // Im -= Tre*Kim
            __builtin_amdgcn_s_setprio(0);
        }
    }
}

template<int IT>
static __device__ __forceinline__ void run_layer(
    const _Float16* __restrict__ kraus,
    const half8 (&a1re)[2][4], const half8 (&a1im)[2][4],
    f32x16 (&accRe)[2], f32x16 (&accIm)[2],
    int lane)
{
    #pragma unroll 1
    for (int k = 0; k < NKR; ++k)
        kstep<IT>(kraus + (size_t)k * 8192, a1re, a1im, accRe, accIm, lane);
}

// One wave per block; grid (NB, 2): blockIdx.x = rho, blockIdx.y = output i-tile.
// No LDS, no barriers: 2048 free-running waves, K fragments read coalesced from L1/L2.
__global__ __launch_bounds__(64, 2) void layer_kernel(
    const _Float16* __restrict__ rho_in,    // fragment-order rho^T, [b][plane][4096]
    _Float16* __restrict__ rho_out,
    float* __restrict__ final_out,
    const _Float16* __restrict__ kraus,     // this layer, fragment order: [K][plane][4096]
    int last)
{
    const int b    = blockIdx.x;
    const int IT   = blockIdx.y;
    const int lane = threadIdx.x;
    const int l31  = lane & 31;
    const int hl   = lane >> 5;

    // ---- hoisted A1: full rho^T fragments (coalesced in fragment layout) ----
    half8 a1re[2][4], a1im[2][4];
    {
        const _Float16* rb = rho_in + (size_t)b * 2 * D * D;
        #pragma unroll
        for (int lh = 0; lh < 2; ++lh)
            #pragma unroll
            for (int ks = 0; ks < 4; ++ks) {
                a1re[lh][ks] = *(const half8*)(rb + lh * 2048 + ks * 512 + lane * 8);
                a1im[lh][ks] = *(const half8*)(rb + 4096 + lh * 2048 + ks * 512 + lane * 8);
            }
    }

    f32x16 accRe[2], accIm[2];
    #pragma unroll
    for (int mt = 0; mt < 2; ++mt)
        #pragma unroll
        for (int i = 0; i < 16; ++i) { accRe[mt][i] = 0.f; accIm[mt][i] = 0.f; }

    if (IT == 0) run_layer<0>(kraus, a1re, a1im, accRe, accIm, lane);
    else         run_layer<1>(kraus, a1re, a1im, accRe, accIm, lane);

    // ---- epilogue: acc lane=col m_rel, reg 4g+j -> row i = 32*IT + 8g + 4hl + j ----
    if (!last) {
        // write rho_new^T in fragment order: row=m=32mt+l31, col=i
        // -> off = plane*4096 + mt*2048 + (4*IT+g)*256 + l31*8 + 4*hl  (+j contiguous)
        _Float16* ob = rho_out + (size_t)b * 2 * D * D;
        #pragma unroll
        for (int mt = 0; mt < 2; ++mt) {
            #pragma unroll
            for (int g = 0; g < 4; ++g) {
                Pack4 pr, pi;
                #pragma unroll
                for (int j = 0; j < 4; ++j) {
                    pr.h[j] = (_Float16)accRe[mt][4 * g + j];
                    pi.h[j] = (_Float16)accIm[mt][4 * g + j];
                }
                const int off = mt * 2048 + (4 * IT + g) * 256 + l31 * 8 + 4 * hl;
                *(uint2*)(ob + off)        = pr.u;
                *(uint2*)(ob + 4096 + off) = pi.u;
            }
        }
    } else {
        float* o0 = final_out + (size_t)b * 4096;            // [0][b][i][m]
        float* o1 = final_out + (size_t)(NB + b) * 4096;     // [1][b][i][m]
        #pragma unroll
        for (int mt = 0; mt < 2; ++mt) {
            const int m = 32 * mt + l31;
            #pragma unroll
            for (int g = 0; g < 4; ++g) {
                #pragma unroll
                for (int j = 0; j < 4; ++j) {
                    const int i = 32 * IT + 8 * g + 4 * hl + j;
                    o0[i * D + m] = accRe[mt][4 * g + j];
                    o1[i * D + m] = accIm[mt][4 * g + j];
                }
            }
        }
    }
}

extern "C" void kernel_launch(void* const* d_in, const int* in_sizes, int n_in,
                              void* d_out, int out_size, void* d_ws, size_t ws_size,
                              hipStream_t stream) {
    const float* state_re = (const float*)d_in[0];
    const float* state_im = (const float*)d_in[1];
    const float* kraus_re = (const float*)d_in[2];
    const float* kraus_im = (const float*)d_in[3];

    _Float16* kraus_h = (_Float16*)d_ws;                         // 2 MB in ws (frag order)
    // ping-pong rho buffers live inside d_out (2 x 16 MB = out_size exactly).
    _Float16* bufA = (_Float16*)d_out;
    _Float16* bufB = (_Float16*)((char*)d_out + (size_t)NB * 2 * D * D * sizeof(_Float16));
    float* fout = (float*)d_out;

    kconv_kernel<<<dim3(512, 2), 256, 0, stream>>>(kraus_re, kraus_im, kraus_h);
    sconv_kernel<<<NB, 256, 0, stream>>>(state_re, state_im, bufA);

    for (int l = 0; l < NL; ++l) {
        const _Float16* in = (l & 1) ? bufB : bufA;
        _Float16* out      = (l & 1) ? bufA : bufB;
        layer_kernel<<<dim3(NB, 2), 64, 0, stream>>>(in, out, fout,
                                                     kraus_h + (size_t)l * NKR * 2 * D * D,
                                                     (l == NL - 1) ? 1 : 0);
    }
}